// Round 6
// baseline (656.004 us; speedup 1.0000x reference)
//
#include <hip/hip_runtime.h>
#include <hip/hip_bf16.h>

// Problem constants (from reference)
#define NN 20000
#define EE 320000
#define FF 75
#define GG 64
#define LL 5
#define EPS 1e-5f

// GEMM paddings
#define KUV 96      // K for uv gemm (h: 75 -> 96; col 75 = 1.0 bias trick)
#define NUV 160     // cols: u at 0..74, v at 80..154
#define KPOST 384   // K for post gemm ([h|agg]: 375 -> 384)
#define KLIN 96

typedef short bf16x8 __attribute__((ext_vector_type(8)));
typedef float f32x4 __attribute__((ext_vector_type(4)));

__device__ inline void gAtomicAdd(float* p, float v) { unsafeAtomicAdd(p, v); }

__device__ inline ushort f2bs(float x) {
    __hip_bfloat16 b = __float2bfloat16(x);
    return *(ushort*)&b;
}

__device__ inline float bs2f(ushort u) {
    unsigned int x = ((unsigned int)u) << 16;
    return __uint_as_float(x);
}

#define S_UV (LL * NUV * KUV)
#define S_POST (LL * 240 * KPOST)
#define S_LIN (LL * 80 * KLIN)
#define S_TOT (S_UV + S_POST + S_LIN)

// ---------------- 1: degree count + weight prep (independent work, merged) ----------------

__global__ void countprep_kernel(const int* __restrict__ col, int* __restrict__ cnt,
                                 const float* __restrict__ pre_w, const float* __restrict__ pre_b,
                                 const float* __restrict__ post_w, const float* __restrict__ lin_w,
                                 ushort* __restrict__ BTuv, ushort* __restrict__ BTpost,
                                 ushort* __restrict__ BTlin) {
    int idx0 = blockIdx.x * 256 + threadIdx.x;
    if (idx0 < EE) {
        atomicAdd(&cnt[col[idx0]], 1);
        return;
    }
    int idx = idx0 - EE;
    if (idx < S_UV) {
        int l = idx / (NUV * KUV);
        int r = idx % (NUV * KUV);
        int c = r / KUV, k = r % KUV;
        float v = 0.f;
        if (k < FF) {
            if (c < FF) v = pre_w[((size_t)l * 150 + k) * FF + c];
            else if (c >= 80 && c < 80 + FF) v = pre_w[((size_t)l * 150 + FF + k) * FF + (c - 80)];
        } else if (k == FF && c < FF) {
            v = pre_b[l * FF + c];  // bias fold: A col75 = 1.0
        }
        BTuv[idx] = f2bs(v);
    } else if (idx < S_UV + S_POST) {
        int j = idx - S_UV;
        int l = j / (240 * KPOST);
        int r = j % (240 * KPOST);
        int c = r / KPOST, k = r % KPOST;
        float v = 0.f;
        if (k < FF) {
            if (c < FF) v = post_w[((size_t)l * 975 + k) * FF + c];
        } else if (k < 375) {
            if (c < FF) v = post_w[((size_t)l * 975 + k) * FF + c];
            else if (c >= 80 && c < 80 + FF) v = post_w[((size_t)l * 975 + k + 300) * FF + (c - 80)];
            else if (c >= 160 && c < 160 + FF) v = post_w[((size_t)l * 975 + k + 600) * FF + (c - 160)];
        }
        BTpost[j] = f2bs(v);
    } else if (idx < S_TOT) {
        int j = idx - S_UV - S_POST;
        int l = j / (80 * KLIN);
        int r = j % (80 * KLIN);
        int c = r / KLIN, k = r % KLIN;
        float v = (c < FF && k < FF) ? lin_w[((size_t)l * FF + k) * FF + c] : 0.f;
        BTlin[j] = f2bs(v);
    }
}

// ---------------- 2: dinv + sumlog + CSR segment alloc (atomic base; order-free CSR) ----------------

__global__ void dinv_offs_kernel(const int* __restrict__ cnt, float* __restrict__ dinv,
                                 float* __restrict__ scal, int* __restrict__ gcur,
                                 int* __restrict__ offs, int* __restrict__ cursor, int N) {
    __shared__ int sh[256];
    __shared__ float red[256];
    __shared__ int bb;
    int tid = threadIdx.x;
    int i = blockIdx.x * 256 + tid;
    int cv = (i < N) ? cnt[i] : 0;
    float lg = 0.f;
    if (i < N) {
        dinv[i] = rsqrtf((float)cv + 1.f);
        lg = logf((float)cv + 1.f);
    }
    sh[tid] = cv;
    red[tid] = lg;
    __syncthreads();
    for (int d = 1; d < 256; d <<= 1) {
        int t = (tid >= d) ? sh[tid - d] : 0;
        __syncthreads();
        sh[tid] += t;
        __syncthreads();
    }
    if (tid == 255) bb = atomicAdd(gcur, sh[255]);
    __syncthreads();
    int excl = sh[tid] - cv + bb;
    if (i < N) {
        offs[i] = excl;
        cursor[i] = excl;
    }
    for (int s = 128; s > 0; s >>= 1) {
        if (tid < s) red[tid] += red[tid + s];
        __syncthreads();
    }
    if (tid == 0) gAtomicAdd(&scal[0], red[0]);
}

// ---------------- 3: CSR fill + xs prescale ----------------

__global__ void fill_xs_kernel(const int* __restrict__ row, const int* __restrict__ col,
                               int* __restrict__ cursor, int* __restrict__ csr,
                               const float* __restrict__ x, const float* __restrict__ gw,
                               const float* __restrict__ dinv, ushort* __restrict__ xs) {
    int idx = blockIdx.x * 256 + threadIdx.x;
    if (idx < EE) {
        int c = col[idx];
        int pos = atomicAdd(&cursor[c], 1);
        csr[pos] = row[idx];
    } else if (idx < EE + NN * 80) {
        int j = idx - EE;
        int n = j / 80, t = j % 80;
        float v = 0.f;
        if (t < FF) {
            float acc = 0.f;
#pragma unroll
            for (int k = 0; k < 6; k++) acc += x[n * 6 + k] * gw[k * FF + t];
            v = dinv[n] * acc;
        }
        xs[j] = f2bs(v);
    }
}

// ---------------- 4: GCN gather + uv GEMM (layer 0) fused; 2 waves, 32 nodes/block ----------------

__global__ __launch_bounds__(128) void gcn_uv_kernel(
    const ushort* __restrict__ xs, const float* __restrict__ dinv,
    const int* __restrict__ offs, const int* __restrict__ csr,
    const float* __restrict__ gcn_b, const int* __restrict__ cnt,
    const float* __restrict__ scal, const ushort* __restrict__ BT,
    float* __restrict__ U, ushort* __restrict__ Vb, ushort* __restrict__ hagg,
    float* __restrict__ amp, float* __restrict__ att) {
    __shared__ __align__(16) float hrow[32][80];
    __shared__ __align__(16) float lred[2][480];
    int tidx = threadIdx.x;
    int wid = tidx >> 6, lane = tidx & 63;
    int n0 = blockIdx.x * 32;
    int w16 = wid * 16;
    int s = lane / 10, f = lane - s * 10;
    float* lw = lred[wid];

    for (int g = 0; g < 16; g++) {
        int i = n0 + w16 + g;
        int s0 = offs[i];
        int deg = cnt[i];
        if (lane < 60) {
            float a[8];
#pragma unroll
            for (int j = 0; j < 8; j++) a[j] = 0.f;
            int full = deg / 6;
            bool tail = (s < deg - full * 6);
            int k = s0 + s;
            int r_nx = (full > 0 || tail) ? csr[k] : 0;
            for (int it = 0; it < full; it++) {
                int r = r_nx;
                k += 6;
                if (it + 1 < full || tail) r_nx = csr[k];
                bf16x8 v = *(const bf16x8*)(xs + (size_t)r * 80 + f * 8);
#pragma unroll
                for (int j = 0; j < 8; j++) a[j] += bs2f((ushort)v[j]);
            }
            if (tail) {
                bf16x8 v = *(const bf16x8*)(xs + (size_t)r_nx * 80 + f * 8);
#pragma unroll
                for (int j = 0; j < 8; j++) a[j] += bs2f((ushort)v[j]);
            }
            *(f32x4*)&lw[s * 80 + f * 8] = (f32x4){a[0], a[1], a[2], a[3]};
            *(f32x4*)&lw[s * 80 + f * 8 + 4] = (f32x4){a[4], a[5], a[6], a[7]};
        }
        __syncthreads();
        if (lane < 40) {
            int t0 = 2 * lane, t1 = t0 + 1;
            float a0 = 0.f, a1 = 0.f;
#pragma unroll
            for (int q = 0; q < 6; q++) {
                float2 pr = *(const float2*)&lw[q * 80 + t0];
                a0 += pr.x;
                a1 += pr.y;
            }
            ushort2 vs = *(const ushort2*)(xs + (size_t)i * 80 + t0);
            a0 += bs2f(vs.x);
            a1 += bs2f(vs.y);
            float di = dinv[i];
            if (t0 < FF) hrow[w16 + g][t0] = di * a0 + gcn_b[t0];
            if (t1 < FF) hrow[w16 + g][t1] = di * a1 + gcn_b[t1];
        } else if (lane == 63) {
            float al = scal[0] / (float)NN;
            float d = fmaxf((float)deg, 1.f);
            float lg = logf(d + 1.f);
            amp[i] = lg / al;
            att[i] = al / lg;
        }
        __syncthreads();
    }

    // uv GEMM: each wave handles its own 16 rows (no BN at layer 0)
    int col16 = lane & 15, quad = lane >> 4;
    const float* orow = &hrow[w16 + col16][0];
    const ushort* bbase = BT + (size_t)col16 * KUV + quad * 8;
    f32x4 acc[10];
#pragma unroll
    for (int i = 0; i < 10; i++) acc[i] = (f32x4){0.f, 0.f, 0.f, 0.f};
#pragma unroll
    for (int kt = 0; kt < 3; kt++) {
        int kb = kt * 32 + quad * 8;
        bf16x8 af;
        if (kb < 80) {
            float4 v0 = *(const float4*)(orow + kb);
            float4 v1 = *(const float4*)(orow + kb + 4);
            float vv[8] = {v0.x, v0.y, v0.z, v0.w, v1.x, v1.y, v1.z, v1.w};
#pragma unroll
            for (int j = 0; j < 8; j++) {
                int k = kb + j;
                ushort h = (k < FF) ? f2bs(vv[j]) : (k == FF ? (ushort)0x3F80 : (ushort)0);
                af[j] = (short)h;
            }
            if (kb < FF)
                *(bf16x8*)(hagg + (size_t)(n0 + w16 + col16) * 80 + kb) = af;
        } else {
            af = (bf16x8){0, 0, 0, 0, 0, 0, 0, 0};
        }
#pragma unroll
        for (int nt = 0; nt < 10; nt++) {
            bf16x8 bfr = *(const bf16x8*)(bbase + nt * (16 * KUV) + kt * 32);
            acc[nt] = __builtin_amdgcn_mfma_f32_16x16x32_bf16(af, bfr, acc[nt], 0, 0, 0);
        }
    }
#pragma unroll
    for (int nt = 0; nt < 10; nt++) {
        int col = nt * 16 + col16;
#pragma unroll
        for (int r = 0; r < 4; r++) {
            int nn = n0 + w16 + quad * 4 + r;
            if (col < FF) U[(size_t)nn * 80 + col] = acc[nt][r];
            else if (col >= 80 && col < 80 + FF) Vb[(size_t)nn * 80 + (col - 80)] = f2bs(acc[nt][r]);
        }
    }
}

// ---------------- uv GEMM + fused BN (layers 1..4): 1 wave = 32 rows ----------------

__global__ __launch_bounds__(64) void uv_bn_kernel(
    const float* __restrict__ o2, const float* __restrict__ slots,
    const float* __restrict__ bg, const float* __restrict__ bb,
    const ushort* __restrict__ BT, float* __restrict__ U, ushort* __restrict__ Vb,
    ushort* __restrict__ hagg) {
    __shared__ float ssL[160];
    int lane = threadIdx.x;
    int col16 = lane & 15, quad = lane >> 4;
    int nA = blockIdx.x * 32 + col16;
    const float* orowA = o2 + (size_t)nA * 80;
    const float* orowB = orowA + 16 * 80;
    const ushort* bbase = BT + (size_t)col16 * KUV + quad * 8;

    for (int c = lane; c < 80; c += 64) {
        if (c < FF) {
            float su = 0.f, sq = 0.f;
#pragma unroll 8
            for (int s = 0; s < 32; s++) {
                su += slots[s * 160 + c];
                sq += slots[s * 160 + 80 + c];
            }
            float mu = su * (1.f / (float)NN);
            float var = sq * (1.f / (float)NN) - mu * mu;
            float sc = bg[c] * rsqrtf(var + EPS);
            ssL[c] = sc;
            ssL[80 + c] = bb[c] - mu * sc;
        } else {
            ssL[c] = 0.f;
            ssL[80 + c] = 0.f;
        }
    }
    __syncthreads();

    f32x4 accA[10], accB[10];
#pragma unroll
    for (int i = 0; i < 10; i++) {
        accA[i] = (f32x4){0.f, 0.f, 0.f, 0.f};
        accB[i] = (f32x4){0.f, 0.f, 0.f, 0.f};
    }

#pragma unroll
    for (int kt = 0; kt < 3; kt++) {
        int kb = kt * 32 + quad * 8;
        bf16x8 afA, afB;
        if (kb < 80) {
            float4 a0 = *(const float4*)(orowA + kb);
            float4 a1 = *(const float4*)(orowA + kb + 4);
            float4 b0 = *(const float4*)(orowB + kb);
            float4 b1 = *(const float4*)(orowB + kb + 4);
            float vA[8] = {a0.x, a0.y, a0.z, a0.w, a1.x, a1.y, a1.z, a1.w};
            float vB[8] = {b0.x, b0.y, b0.z, b0.w, b1.x, b1.y, b1.z, b1.w};
#pragma unroll
            for (int j = 0; j < 8; j++) {
                int k = kb + j;
                float xA = fmaxf(vA[j] * ssL[k] + ssL[80 + k], 0.f);
                float xB = fmaxf(vB[j] * ssL[k] + ssL[80 + k], 0.f);
                ushort hA = (k < FF) ? f2bs(xA) : (k == FF ? (ushort)0x3F80 : (ushort)0);
                ushort hB = (k < FF) ? f2bs(xB) : (k == FF ? (ushort)0x3F80 : (ushort)0);
                afA[j] = (short)hA;
                afB[j] = (short)hB;
            }
            if (kb < FF) {
                *(bf16x8*)(hagg + (size_t)nA * 80 + kb) = afA;
                *(bf16x8*)(hagg + (size_t)(nA + 16) * 80 + kb) = afB;
            }
        } else {
            afA = (bf16x8){0, 0, 0, 0, 0, 0, 0, 0};
            afB = (bf16x8){0, 0, 0, 0, 0, 0, 0, 0};
        }
#pragma unroll
        for (int nt = 0; nt < 10; nt++) {
            bf16x8 bfr = *(const bf16x8*)(bbase + nt * (16 * KUV) + kt * 32);
            accA[nt] = __builtin_amdgcn_mfma_f32_16x16x32_bf16(afA, bfr, accA[nt], 0, 0, 0);
            accB[nt] = __builtin_amdgcn_mfma_f32_16x16x32_bf16(afB, bfr, accB[nt], 0, 0, 0);
        }
    }
    int n0 = blockIdx.x * 32;
#pragma unroll
    for (int nt = 0; nt < 10; nt++) {
        int col = nt * 16 + col16;
#pragma unroll
        for (int r = 0; r < 4; r++) {
            int nnA = n0 + quad * 4 + r;
            int nnB = nnA + 16;
            if (col < FF) {
                U[(size_t)nnA * 80 + col] = accA[nt][r];
                U[(size_t)nnB * 80 + col] = accB[nt][r];
            } else if (col >= 80 && col < 80 + FF) {
                Vb[(size_t)nnA * 80 + (col - 80)] = f2bs(accA[nt][r]);
                Vb[(size_t)nnB * 80 + (col - 80)] = f2bs(accB[nt][r]);
            }
        }
    }
}

// ---------------- edge agg + post GEMM + lin GEMM + BN stats fused; 2 waves, 32 nodes ----------------

__global__ __launch_bounds__(128) void aggpost_kernel(
    const ushort* __restrict__ hagg, const float* __restrict__ U,
    const ushort* __restrict__ V, const int* __restrict__ offs,
    const int* __restrict__ csr, const int* __restrict__ cnt,
    const ushort* __restrict__ BT, const ushort* __restrict__ BL,
    const float* __restrict__ amp, const float* __restrict__ att,
    float* __restrict__ o2, float* __restrict__ slots) {
    __shared__ __align__(16) ushort arow[32][392];  // 392 pad: 2-way LDS banks on A reads
    __shared__ __align__(16) float sc4[2][4][480];
    __shared__ __align__(16) ushort olds[32][104];
    int tidx = threadIdx.x;
    int wid = tidx >> 6, lane = tidx & 63;
    int n0 = blockIdx.x * 32;
    int w16 = wid * 16;

    // copy h-cols (0..79) from global hagg; pad cols 375..383
    for (int idx = tidx; idx < 32 * 10; idx += 128) {
        int r = idx / 10, oct = idx % 10;
        *(bf16x8*)&arow[r][oct * 8] = *(const bf16x8*)(hagg + (size_t)(n0 + r) * 80 + oct * 8);
    }
    if (tidx < 32) {
        arow[tidx][375] = 0;
        *(bf16x8*)&arow[tidx][376] = (bf16x8){0, 0, 0, 0, 0, 0, 0, 0};
    }
    __syncthreads();

    int s = lane / 10, f = lane - s * 10;
    float* lsa = sc4[wid][0];
    float* lsq = sc4[wid][1];
    float* lmn = sc4[wid][2];
    float* lmx = sc4[wid][3];

    for (int g = 0; g < 16; g++) {
        int i = n0 + w16 + g;
        int s0 = offs[i];
        int deg = cnt[i];
        if (lane < 60) {
            float sa[8], sq[8], mn[8], mx[8];
#pragma unroll
            for (int j = 0; j < 8; j++) {
                sa[j] = 0.f; sq[j] = 0.f; mn[j] = 1e30f; mx[j] = -1e30f;
            }
            int full = deg / 6;
            bool tail = (s < deg - full * 6);
            int k = s0 + s;
            int r_nx = (full > 0 || tail) ? csr[k] : 0;
            for (int it = 0; it < full; it++) {
                int r = r_nx;
                k += 6;
                if (it + 1 < full || tail) r_nx = csr[k];
                bf16x8 v = *(const bf16x8*)(V + (size_t)r * 80 + f * 8);
#pragma unroll
                for (int j = 0; j < 8; j++) {
                    float xv = bs2f((ushort)v[j]);
                    sa[j] += xv;
                    sq[j] += xv * xv;
                    mn[j] = fminf(mn[j], xv);
                    mx[j] = fmaxf(mx[j], xv);
                }
            }
            if (tail) {
                bf16x8 v = *(const bf16x8*)(V + (size_t)r_nx * 80 + f * 8);
#pragma unroll
                for (int j = 0; j < 8; j++) {
                    float xv = bs2f((ushort)v[j]);
                    sa[j] += xv;
                    sq[j] += xv * xv;
                    mn[j] = fminf(mn[j], xv);
                    mx[j] = fmaxf(mx[j], xv);
                }
            }
            *(f32x4*)&lsa[s * 80 + f * 8] = (f32x4){sa[0], sa[1], sa[2], sa[3]};
            *(f32x4*)&lsa[s * 80 + f * 8 + 4] = (f32x4){sa[4], sa[5], sa[6], sa[7]};
            *(f32x4*)&lsq[s * 80 + f * 8] = (f32x4){sq[0], sq[1], sq[2], sq[3]};
            *(f32x4*)&lsq[s * 80 + f * 8 + 4] = (f32x4){sq[4], sq[5], sq[6], sq[7]};
            *(f32x4*)&lmn[s * 80 + f * 8] = (f32x4){mn[0], mn[1], mn[2], mn[3]};
            *(f32x4*)&lmn[s * 80 + f * 8 + 4] = (f32x4){mn[4], mn[5], mn[6], mn[7]};
            *(f32x4*)&lmx[s * 80 + f * 8] = (f32x4){mx[0], mx[1], mx[2], mx[3]};
            *(f32x4*)&lmx[s * 80 + f * 8 + 4] = (f32x4){mx[4], mx[5], mx[6], mx[7]};
        }
        __syncthreads();
        if (lane < 40) {
            int t0 = 2 * lane, t1 = t0 + 1;
            float sa0 = 0.f, sq0 = 0.f, mn0 = 1e30f, mx0 = -1e30f;
            float sa1 = 0.f, sq1 = 0.f, mn1 = 1e30f, mx1 = -1e30f;
#pragma unroll
            for (int q = 0; q < 6; q++) {
                float2 pa = *(const float2*)&lsa[q * 80 + t0];
                float2 pq = *(const float2*)&lsq[q * 80 + t0];
                float2 pn = *(const float2*)&lmn[q * 80 + t0];
                float2 px = *(const float2*)&lmx[q * 80 + t0];
                sa0 += pa.x; sa1 += pa.y;
                sq0 += pq.x; sq1 += pq.y;
                mn0 = fminf(mn0, pn.x); mn1 = fminf(mn1, pn.y);
                mx0 = fmaxf(mx0, px.x); mx1 = fmaxf(mx1, px.y);
            }
            float cf = (float)deg;
            float cc = fmaxf(cf, 1.f);
            float2 u2 = *(const float2*)(U + (size_t)i * 80 + t0);
            ushort* a = &arow[w16 + g][FF];
            {
                float mean = (u2.x * cf + sa0) / cc;
                float ev = sa0 / cc;
                float stdv = sqrtf(fmaxf(sq0 / cc - ev * ev, 0.f) + EPS);
                float mno = (deg > 0) ? (u2.x + mn0) : 0.f;
                float mxo = (deg > 0) ? (u2.x + mx0) : 0.f;
                if (t0 < FF) {
                    a[t0] = f2bs(mean);
                    a[FF + t0] = f2bs(mno);
                    a[2 * FF + t0] = f2bs(mxo);
                    a[3 * FF + t0] = f2bs(stdv);
                }
            }
            {
                float mean = (u2.y * cf + sa1) / cc;
                float ev = sa1 / cc;
                float stdv = sqrtf(fmaxf(sq1 / cc - ev * ev, 0.f) + EPS);
                float mno = (deg > 0) ? (u2.y + mn1) : 0.f;
                float mxo = (deg > 0) ? (u2.y + mx1) : 0.f;
                if (t1 < FF) {
                    a[t1] = f2bs(mean);
                    a[FF + t1] = f2bs(mno);
                    a[2 * FF + t1] = f2bs(mxo);
                    a[3 * FF + t1] = f2bs(stdv);
                }
            }
        }
        __syncthreads();
    }

    // post GEMM from LDS A rows; each wave its own 16 rows
    int col16 = lane & 15, quad = lane >> 4, kseg = quad * 8;
    const ushort* bbase = BT + (size_t)col16 * KPOST + kseg;
    f32x4 acc[15];
#pragma unroll
    for (int i = 0; i < 15; i++) acc[i] = (f32x4){0.f, 0.f, 0.f, 0.f};
#pragma unroll 2
    for (int kt = 0; kt < 12; kt++) {
        bf16x8 af = *(const bf16x8*)(&arow[w16 + col16][kt * 32 + kseg]);
#pragma unroll
        for (int nt = 0; nt < 15; nt++) {
            bf16x8 bfr = *(const bf16x8*)(bbase + (size_t)nt * (16 * KPOST) + kt * 32);
            acc[nt] = __builtin_amdgcn_mfma_f32_16x16x32_bf16(af, bfr, acc[nt], 0, 0, 0);
        }
    }
    float ampv[4], attv[4];
#pragma unroll
    for (int r = 0; r < 4; r++) {
        int n = n0 + w16 + quad * 4 + r;
        ampv[r] = amp[n];
        attv[r] = att[n];
    }
#pragma unroll
    for (int g5 = 0; g5 < 5; g5++) {
        int col = g5 * 16 + col16;
#pragma unroll
        for (int r = 0; r < 4; r++) {
            float ov = acc[g5][r] + ampv[r] * acc[g5 + 5][r] + attv[r] * acc[g5 + 10][r];
            olds[w16 + quad * 4 + r][col] = (col < FF) ? f2bs(ov) : (ushort)0;
        }
    }
    if (lane < 32) {
        int rr = w16 + (lane >> 1), cc = 80 + (lane & 1) * 8;
        *(bf16x8*)&olds[rr][cc] = (bf16x8){0, 0, 0, 0, 0, 0, 0, 0};
    }
    __syncthreads();

    // lin GEMM (K=96)
    f32x4 acc2[5];
#pragma unroll
    for (int i = 0; i < 5; i++) acc2[i] = (f32x4){0.f, 0.f, 0.f, 0.f};
    const ushort* blbase = BL + (size_t)col16 * KLIN + kseg;
#pragma unroll
    for (int kt = 0; kt < 3; kt++) {
        bf16x8 af = *(const bf16x8*)(&olds[w16 + col16][kt * 32 + kseg]);
#pragma unroll
        for (int nt = 0; nt < 5; nt++) {
            bf16x8 bfr = *(const bf16x8*)(blbase + nt * (16 * KLIN) + kt * 32);
            acc2[nt] = __builtin_amdgcn_mfma_f32_16x16x32_bf16(af, bfr, acc2[nt], 0, 0, 0);
        }
    }
    // epilogue: o2 + BN partial sums
    float* slot = slots + (blockIdx.x & 31) * 160;
#pragma unroll
    for (int nt = 0; nt < 5; nt++) {
        int col = nt * 16 + col16;
        float sv = 0.f, qv = 0.f;
#pragma unroll
        for (int r = 0; r < 4; r++) {
            int nn = n0 + w16 + quad * 4 + r;
            float v = acc2[nt][r];
            if (col < FF) {
                o2[(size_t)nn * 80 + col] = v;
                sv += v;
                qv += v * v;
            }
        }
        sv += __shfl_xor(sv, 16); sv += __shfl_xor(sv, 32);
        qv += __shfl_xor(qv, 16); qv += __shfl_xor(qv, 32);
        if (lane < 16 && col < FF) {
            gAtomicAdd(&slot[col], sv);
            gAtomicAdd(&slot[80 + col], qv);
        }
    }
}

// ---------------- pool (BN inline) + final MLP fused: one block per graph ----------------

__global__ __launch_bounds__(256) void pool_mlp_kernel(
    const float* __restrict__ o2, const float* __restrict__ slots,
    const float* __restrict__ bg, const float* __restrict__ bb,
    const int* __restrict__ batch,
    const float* __restrict__ w1, const float* __restrict__ b1,
    const float* __restrict__ w2, const float* __restrict__ b2,
    const float* __restrict__ w3, const float* __restrict__ b3,
    float* __restrict__ out) {
    __shared__ float ssL[160];
    __shared__ float part[3][80];
    __shared__ float gr[80], h1[50], h2[25];
    int gi = blockIdx.x, tid = threadIdx.x;
    for (int c = tid; c < 80; c += 256) {
        if (c < FF) {
            float su = 0.f, sq = 0.f;
#pragma unroll 8
            for (int s = 0; s < 32; s++) {
                su += slots[s * 160 + c];
                sq += slots[s * 160 + 80 + c];
            }
            float mu = su * (1.f / (float)NN);
            float var = sq * (1.f / (float)NN) - mu * mu;
            float sc = bg[c] * rsqrtf(var + EPS);
            ssL[c] = sc;
            ssL[80 + c] = bb[c] - mu * sc;
        } else {
            ssL[c] = 0.f;
            ssL[80 + c] = 0.f;
        }
    }
    __syncthreads();
    // node range for this graph (batch sorted)
    int lo, hi;
    {
        int a = 0, b = NN;
        while (a < b) { int m = (a + b) >> 1; if (batch[m] < gi) a = m + 1; else b = m; }
        lo = a;
        b = NN;
        while (a < b) { int m = (a + b) >> 1; if (batch[m] < gi + 1) a = m + 1; else b = m; }
        hi = a;
    }
    if (tid < 240) {
        int c = tid % 80, sub = tid / 80;
        float acc = 0.f;
        if (c < FF) {
            for (int n = lo + sub; n < hi; n += 3)
                acc += fmaxf(o2[(size_t)n * 80 + c] * ssL[c] + ssL[80 + c], 0.f);
        }
        part[sub][c] = acc;
    }
    __syncthreads();
    if (tid < 80) gr[tid] = part[0][tid] + part[1][tid] + part[2][tid];
    __syncthreads();
    if (tid < 50) {
        float a = b1[tid];
        for (int k = 0; k < FF; k++) a += gr[k] * w1[k * 50 + tid];
        h1[tid] = fmaxf(a, 0.f);
    }
    __syncthreads();
    if (tid < 25) {
        float a = b2[tid];
        for (int k = 0; k < 50; k++) a += h1[k] * w2[k * 25 + tid];
        h2[tid] = fmaxf(a, 0.f);
    }
    __syncthreads();
    if (tid < 10) {
        float a = b3[tid];
        for (int k = 0; k < 25; k++) a += h2[k] * w3[k * 10 + tid];
        out[gi * 10 + tid] = a;
    }
}

// ---------------- launch ----------------

extern "C" void kernel_launch(void* const* d_in, const int* in_sizes, int n_in,
                              void* d_out, int out_size, void* d_ws, size_t ws_size,
                              hipStream_t stream) {
    const float* x = (const float*)d_in[0];
    const int* ei = (const int*)d_in[1];
    const int* batch = (const int*)d_in[2];
    const float* gcn_w = (const float*)d_in[3];
    const float* gcn_b = (const float*)d_in[4];
    const float* pre_w = (const float*)d_in[5];
    const float* pre_b = (const float*)d_in[6];
    const float* post_w = (const float*)d_in[7];
    const float* lin_w = (const float*)d_in[9];
    const float* bn_g = (const float*)d_in[11];
    const float* bn_b = (const float*)d_in[12];
    const float* w1 = (const float*)d_in[13];
    const float* b1 = (const float*)d_in[14];
    const float* w2 = (const float*)d_in[15];
    const float* b2 = (const float*)d_in[16];
    const float* w3 = (const float*)d_in[17];
    const float* b3 = (const float*)d_in[18];
    float* out = (float*)d_out;

    const int* row = ei;
    const int* col = ei + EE;

    char* ws = (char*)d_ws;
    size_t off = 0;
    auto alloc = [&](size_t bytes) {
        char* p = ws + off;
        off += (bytes + 255) & ~(size_t)255;
        return p;
    };
    // zero-region: cnt + scal(+slots) + gcur adjacent, single memset
    size_t z0 = off;
    int* cnt = (int*)alloc(NN * 4);
    float* scal = (float*)alloc((1 + LL * 32 * 160) * 4);  // [0]=sumlog; slots[5][32][160]
    int* gcur = (int*)alloc(256);
    size_t z1 = off;
    float* slotbase = scal + 1;
    int* offs = (int*)alloc(NN * 4);
    int* cursor = (int*)alloc(NN * 4);
    int* csr = (int*)alloc(EE * 4);
    float* dinv = (float*)alloc(NN * 4);
    float* amp = (float*)alloc(NN * 4);
    float* att = (float*)alloc(NN * 4);
    float* o2 = (float*)alloc((size_t)NN * 80 * 4);
    float* ubuf = (float*)alloc((size_t)NN * 80 * 4);
    ushort* xsbuf = (ushort*)alloc((size_t)NN * 80 * 2);  // GCN-prescaled features
    ushort* vbuf = (ushort*)alloc((size_t)NN * 80 * 2);   // V (bf16) per layer
    ushort* hagg = (ushort*)alloc((size_t)NN * 80 * 2);   // h-cols only (bf16)
    ushort* BTuv = (ushort*)alloc((size_t)S_UV * 2);
    ushort* BTpost = (ushort*)alloc((size_t)S_POST * 2);
    ushort* BTlin = (ushort*)alloc((size_t)S_LIN * 2);

    hipMemsetAsync(ws + z0, 0, z1 - z0, stream);

    const int B = 256;
    const int NB = (NN + 255) / 256;  // 79
    countprep_kernel<<<(EE + S_TOT + B - 1) / B, B, 0, stream>>>(col, cnt, pre_w, pre_b,
                                                                 post_w, lin_w,
                                                                 BTuv, BTpost, BTlin);
    dinv_offs_kernel<<<NB, B, 0, stream>>>(cnt, dinv, scal, gcur, offs, cursor, NN);
    fill_xs_kernel<<<(EE + NN * 80 + B - 1) / B, B, 0, stream>>>(row, col, cursor, csr,
                                                                 x, gcn_w, dinv, xsbuf);

    const int GS = NN / 32;  // 625 blocks, 32 nodes each (exact)
    gcn_uv_kernel<<<GS, 128, 0, stream>>>(xsbuf, dinv, offs, csr, gcn_b, cnt, scal,
                                          BTuv, ubuf, vbuf, hagg, amp, att);
    for (int l = 0; l < LL; l++) {
        float* slots = slotbase + (size_t)l * 32 * 160;
        if (l > 0) {
            const float* sp = slotbase + (size_t)(l - 1) * 32 * 160;
            uv_bn_kernel<<<GS, 64, 0, stream>>>(o2, sp, bn_g + (l - 1) * FF, bn_b + (l - 1) * FF,
                                                BTuv + (size_t)l * NUV * KUV, ubuf, vbuf, hagg);
        }
        aggpost_kernel<<<GS, 128, 0, stream>>>(hagg, ubuf, vbuf, offs, csr, cnt,
                                               BTpost + (size_t)l * 240 * KPOST,
                                               BTlin + (size_t)l * 80 * KLIN,
                                               amp, att, o2, slots);
    }

    pool_mlp_kernel<<<GG, 256, 0, stream>>>(o2, slotbase + (size_t)(LL - 1) * 32 * 160,
                                            bn_g + (LL - 1) * FF, bn_b + (LL - 1) * FF,
                                            batch, w1, b1, w2, b2, w3, b3, out);
}

// Round 7
// 511.191 us; speedup vs baseline: 1.2833x; 1.2833x over previous
//
#include <hip/hip_runtime.h>
#include <hip/hip_bf16.h>

// Problem constants (from reference)
#define NN 20000
#define EE 320000
#define FF 75
#define GG 64
#define LL 5
#define EPS 1e-5f

// GEMM paddings
#define KUV 96      // K for uv gemm (h: 75 -> 96; col 75 = 1.0 bias trick)
#define NUV 160     // cols: u at 0..79, v at 80..159 (full width, pads finite)
#define KPOST 416   // K for post gemm: [h:0..79|mean:80|min:160|max:240|std:320|pad:400..415]
#define KLIN 96

typedef short bf16x8 __attribute__((ext_vector_type(8)));
typedef float f32x4 __attribute__((ext_vector_type(4)));

__device__ inline void gAtomicAdd(float* p, float v) { unsafeAtomicAdd(p, v); }

__device__ inline ushort f2bs(float x) {
    __hip_bfloat16 b = __float2bfloat16(x);
    return *(ushort*)&b;
}

__device__ inline float bs2f(ushort u) {
    unsigned int x = ((unsigned int)u) << 16;
    return __uint_as_float(x);
}

#define S_UV (LL * NUV * KUV)
#define S_POST (LL * 240 * KPOST)
#define S_LIN (LL * 80 * KLIN)
#define S_TOT (S_UV + S_POST + S_LIN)

// ---------------- 1: degree count + weight prep (independent work, merged) ----------------

__global__ void countprep_kernel(const int* __restrict__ col, int* __restrict__ cnt,
                                 const float* __restrict__ pre_w, const float* __restrict__ pre_b,
                                 const float* __restrict__ post_w, const float* __restrict__ lin_w,
                                 ushort* __restrict__ BTuv, ushort* __restrict__ BTpost,
                                 ushort* __restrict__ BTlin) {
    int idx0 = blockIdx.x * 256 + threadIdx.x;
    if (idx0 < EE) {
        atomicAdd(&cnt[col[idx0]], 1);
        return;
    }
    int idx = idx0 - EE;
    if (idx < S_UV) {
        int l = idx / (NUV * KUV);
        int r = idx % (NUV * KUV);
        int c = r / KUV, k = r % KUV;
        float v = 0.f;
        if (k < FF) {
            if (c < FF) v = pre_w[((size_t)l * 150 + k) * FF + c];
            else if (c >= 80 && c < 80 + FF) v = pre_w[((size_t)l * 150 + FF + k) * FF + (c - 80)];
        } else if (k == FF && c < FF) {
            v = pre_b[l * FF + c];  // bias fold: A col75 = 1.0
        }
        BTuv[idx] = f2bs(v);
    } else if (idx < S_UV + S_POST) {
        int j = idx - S_UV;
        int l = j / (240 * KPOST);
        int r = j % (240 * KPOST);
        int c = r / KPOST, k = r % KPOST;
        // K-axis map: h 0..74 | mean 80..154 | min 160..234 | max 240..314 | std 320..394 | else 0
        int rw = -1;
        if (k < FF) rw = k;
        else if (k >= 80 && k < 80 + FF) rw = FF + (k - 80);
        else if (k >= 160 && k < 160 + FF) rw = 2 * FF + (k - 160);
        else if (k >= 240 && k < 240 + FF) rw = 3 * FF + (k - 240);
        else if (k >= 320 && k < 320 + FF) rw = 4 * FF + (k - 320);
        float v = 0.f;
        if (rw >= 0) {
            if (rw < FF) {  // h rows: plain only
                if (c < FF) v = post_w[((size_t)l * 975 + rw) * FF + c];
            } else {        // agg rows: plain / *amp(+300) / *att(+600)
                if (c < FF) v = post_w[((size_t)l * 975 + rw) * FF + c];
                else if (c >= 80 && c < 80 + FF) v = post_w[((size_t)l * 975 + rw + 300) * FF + (c - 80)];
                else if (c >= 160 && c < 160 + FF) v = post_w[((size_t)l * 975 + rw + 600) * FF + (c - 160)];
            }
        }
        BTpost[j] = f2bs(v);
    } else if (idx < S_TOT) {
        int j = idx - S_UV - S_POST;
        int l = j / (80 * KLIN);
        int r = j % (80 * KLIN);
        int c = r / KLIN, k = r % KLIN;
        float v = (c < FF && k < FF) ? lin_w[((size_t)l * FF + k) * FF + c] : 0.f;
        BTlin[j] = f2bs(v);
    }
}

// ---------------- 2: dinv + sumlog + CSR segment alloc (atomic base) ----------------

__global__ void dinv_offs_kernel(const int* __restrict__ cnt, float* __restrict__ dinv,
                                 float* __restrict__ scal, int* __restrict__ gcur,
                                 int* __restrict__ offs, int* __restrict__ cursor, int N) {
    __shared__ int sh[256];
    __shared__ float red[256];
    __shared__ int bb;
    int tid = threadIdx.x;
    int i = blockIdx.x * 256 + tid;
    int cv = (i < N) ? cnt[i] : 0;
    float lg = 0.f;
    if (i < N) {
        dinv[i] = rsqrtf((float)cv + 1.f);
        lg = logf((float)cv + 1.f);
    }
    sh[tid] = cv;
    red[tid] = lg;
    __syncthreads();
    for (int d = 1; d < 256; d <<= 1) {
        int t = (tid >= d) ? sh[tid - d] : 0;
        __syncthreads();
        sh[tid] += t;
        __syncthreads();
    }
    if (tid == 255) bb = atomicAdd(gcur, sh[255]);
    __syncthreads();
    int excl = sh[tid] - cv + bb;
    if (i < N) {
        offs[i] = excl;
        cursor[i] = excl;
    }
    for (int s = 128; s > 0; s >>= 1) {
        if (tid < s) red[tid] += red[tid + s];
        __syncthreads();
    }
    if (tid == 0) gAtomicAdd(&scal[0], red[0]);
}

// ---------------- 3: CSR fill + xs prescale ----------------

__global__ void fill_xs_kernel(const int* __restrict__ row, const int* __restrict__ col,
                               int* __restrict__ cursor, int* __restrict__ csr,
                               const float* __restrict__ x, const float* __restrict__ gw,
                               const float* __restrict__ dinv, ushort* __restrict__ xs) {
    int idx = blockIdx.x * 256 + threadIdx.x;
    if (idx < EE) {
        int c = col[idx];
        int pos = atomicAdd(&cursor[c], 1);
        csr[pos] = row[idx];
    } else if (idx < EE + NN * 80) {
        int j = idx - EE;
        int n = j / 80, t = j % 80;
        float v = 0.f;
        if (t < FF) {
            float acc = 0.f;
#pragma unroll
            for (int k = 0; k < 6; k++) acc += x[n * 6 + k] * gw[k * FF + t];
            v = dinv[n] * acc;
        }
        xs[j] = f2bs(v);
    }
}

// ---------------- 4: GCN gather — 1 node/wave, shuffle merge, zero LDS ----------------

__global__ __launch_bounds__(256) void gcn_kernel(
    const ushort* __restrict__ xs, const float* __restrict__ dinv,
    const int* __restrict__ offs, const int* __restrict__ csr,
    const float* __restrict__ gcn_b, const int* __restrict__ cnt,
    const float* __restrict__ scal, float* __restrict__ o2,
    float* __restrict__ amp, float* __restrict__ att) {
    int wid = threadIdx.x >> 6, lane = threadIdx.x & 63;
    int i = blockIdx.x * 4 + wid;
    int s = lane / 10, f = lane - s * 10;
    int deg = cnt[i];
    int s0 = offs[i];
    float a[8];
#pragma unroll
    for (int j = 0; j < 8; j++) a[j] = 0.f;

    if (lane < 60) {
        int full = deg / 6;
        int rem = deg - full * 6;
        int iters = full + (s < rem ? 1 : 0);
        int k = s0 + s;
        int r_cur = (iters > 0) ? csr[k] : 0;
        int r_nxt = (iters > 1) ? csr[k + 6] : 0;
        bf16x8 v_cur = *(const bf16x8*)(xs + (size_t)r_cur * 80 + f * 8);
        for (int it = 0; it < iters; it++) {
            int r_fut = (it + 2 < iters) ? csr[k + 12] : 0;
            bf16x8 v_nxt = *(const bf16x8*)(xs + (size_t)r_nxt * 80 + f * 8);
#pragma unroll
            for (int j = 0; j < 8; j++) a[j] += bs2f((ushort)v_cur[j]);
            v_cur = v_nxt;
            r_nxt = r_fut;
            k += 6;
        }
    }
    // merge slots 3..5 into 0..2, then 1,2 into 0
#pragma unroll
    for (int j = 0; j < 8; j++) a[j] += __shfl(a[j], lane + 30);
#pragma unroll
    for (int j = 0; j < 8; j++) a[j] += __shfl(a[j], lane + 10) + __shfl(a[j], lane + 20);

    if (lane < 10) {
        bf16x8 vs = *(const bf16x8*)(xs + (size_t)i * 80 + lane * 8);
        float di = dinv[i];
        float o[8];
#pragma unroll
        for (int j = 0; j < 8; j++) {
            int c = lane * 8 + j;
            float bias = (c < FF) ? gcn_b[c] : 0.f;
            o[j] = di * (a[j] + bs2f((ushort)vs[j])) + bias;
        }
        float* orow = o2 + (size_t)i * 80 + lane * 8;
        *(f32x4*)orow = (f32x4){o[0], o[1], o[2], o[3]};
        *(f32x4*)(orow + 4) = (f32x4){o[4], o[5], o[6], o[7]};
    } else if (lane == 60) {
        float al = scal[0] / (float)NN;
        float d = fmaxf((float)deg, 1.f);
        float lg = logf(d + 1.f);
        amp[i] = lg / al;
        att[i] = al / lg;
    }
}

// ---------------- uv GEMM (+ fused BN for l>0): 1 wave = 32 rows ----------------

__global__ __launch_bounds__(64) void uv_bn_kernel(
    const float* __restrict__ o2, const float* __restrict__ slots,
    const float* __restrict__ bg, const float* __restrict__ bb, int apply_bn,
    const ushort* __restrict__ BT, float* __restrict__ U, ushort* __restrict__ Vb,
    ushort* __restrict__ hagg) {
    __shared__ float ssL[160];
    int lane = threadIdx.x;
    int col16 = lane & 15, quad = lane >> 4;
    int nA = blockIdx.x * 32 + col16;
    const float* orowA = o2 + (size_t)nA * 80;
    const float* orowB = orowA + 16 * 80;
    const ushort* bbase = BT + (size_t)col16 * KUV + quad * 8;

    if (apply_bn) {
        for (int c = lane; c < 80; c += 64) {
            if (c < FF) {
                float su = 0.f, sq = 0.f;
#pragma unroll 8
                for (int s = 0; s < 32; s++) {
                    su += slots[s * 160 + c];
                    sq += slots[s * 160 + 80 + c];
                }
                float mu = su * (1.f / (float)NN);
                float var = sq * (1.f / (float)NN) - mu * mu;
                float sc = bg[c] * rsqrtf(var + EPS);
                ssL[c] = sc;
                ssL[80 + c] = bb[c] - mu * sc;
            } else {
                ssL[c] = 0.f;
                ssL[80 + c] = 0.f;
            }
        }
        __syncthreads();
    }

    f32x4 accA[10], accB[10];
#pragma unroll
    for (int i = 0; i < 10; i++) {
        accA[i] = (f32x4){0.f, 0.f, 0.f, 0.f};
        accB[i] = (f32x4){0.f, 0.f, 0.f, 0.f};
    }

#pragma unroll
    for (int kt = 0; kt < 3; kt++) {
        int kb = kt * 32 + quad * 8;
        bf16x8 afA, afB;
        if (kb < 80) {
            float4 a0 = *(const float4*)(orowA + kb);
            float4 a1 = *(const float4*)(orowA + kb + 4);
            float4 b0 = *(const float4*)(orowB + kb);
            float4 b1 = *(const float4*)(orowB + kb + 4);
            float vA[8] = {a0.x, a0.y, a0.z, a0.w, a1.x, a1.y, a1.z, a1.w};
            float vB[8] = {b0.x, b0.y, b0.z, b0.w, b1.x, b1.y, b1.z, b1.w};
#pragma unroll
            for (int j = 0; j < 8; j++) {
                int k = kb + j;
                float xA = vA[j], xB = vB[j];
                if (apply_bn) {
                    xA = fmaxf(xA * ssL[k] + ssL[80 + k], 0.f);
                    xB = fmaxf(xB * ssL[k] + ssL[80 + k], 0.f);
                }
                ushort hA = (k < FF) ? f2bs(xA) : (k == FF ? (ushort)0x3F80 : (ushort)0);
                ushort hB = (k < FF) ? f2bs(xB) : (k == FF ? (ushort)0x3F80 : (ushort)0);
                afA[j] = (short)hA;
                afB[j] = (short)hB;
            }
            if (kb < FF) {
                *(bf16x8*)(hagg + (size_t)nA * KPOST + kb) = afA;
                *(bf16x8*)(hagg + (size_t)(nA + 16) * KPOST + kb) = afB;
            }
        } else {
            afA = (bf16x8){0, 0, 0, 0, 0, 0, 0, 0};
            afB = (bf16x8){0, 0, 0, 0, 0, 0, 0, 0};
        }
#pragma unroll
        for (int nt = 0; nt < 10; nt++) {
            bf16x8 bfr = *(const bf16x8*)(bbase + nt * (16 * KUV) + kt * 32);
            accA[nt] = __builtin_amdgcn_mfma_f32_16x16x32_bf16(afA, bfr, accA[nt], 0, 0, 0);
            accB[nt] = __builtin_amdgcn_mfma_f32_16x16x32_bf16(afB, bfr, accB[nt], 0, 0, 0);
        }
    }
    int n0 = blockIdx.x * 32;
    // full-width epilogue: U cols 0..79 (75..79 = 0, B-zero backed), V cols 0..79 likewise
#pragma unroll
    for (int nt = 0; nt < 10; nt++) {
        int col = nt * 16 + col16;
#pragma unroll
        for (int r = 0; r < 4; r++) {
            int nnA = n0 + quad * 4 + r;
            int nnB = nnA + 16;
            if (col < 80) {
                U[(size_t)nnA * 80 + col] = accA[nt][r];
                U[(size_t)nnB * 80 + col] = accB[nt][r];
            } else {
                Vb[(size_t)nnA * 80 + (col - 80)] = f2bs(accA[nt][r]);
                Vb[(size_t)nnB * 80 + (col - 80)] = f2bs(accB[nt][r]);
            }
        }
    }
}

// ---------------- edge aggregation — 1 node/wave, shuffle merge, zero LDS ----------------

__global__ __launch_bounds__(256) void edge_agg_kernel(
    const float* __restrict__ U, const ushort* __restrict__ V,
    const int* __restrict__ offs, const int* __restrict__ csr,
    const int* __restrict__ cnt, ushort* __restrict__ hagg) {
    int wid = threadIdx.x >> 6, lane = threadIdx.x & 63;
    int i = blockIdx.x * 4 + wid;
    int s = lane / 10, f = lane - s * 10;
    int deg = cnt[i];
    int s0 = offs[i];
    float sa[8], sq[8], mn[8], mx[8];
#pragma unroll
    for (int j = 0; j < 8; j++) {
        sa[j] = 0.f; sq[j] = 0.f; mn[j] = 1e30f; mx[j] = -1e30f;
    }

    if (lane < 60) {
        int full = deg / 6;
        int rem = deg - full * 6;
        int iters = full + (s < rem ? 1 : 0);
        int k = s0 + s;
        int r_cur = (iters > 0) ? csr[k] : 0;
        int r_nxt = (iters > 1) ? csr[k + 6] : 0;
        bf16x8 v_cur = *(const bf16x8*)(V + (size_t)r_cur * 80 + f * 8);
        for (int it = 0; it < iters; it++) {
            int r_fut = (it + 2 < iters) ? csr[k + 12] : 0;
            bf16x8 v_nxt = *(const bf16x8*)(V + (size_t)r_nxt * 80 + f * 8);
#pragma unroll
            for (int j = 0; j < 8; j++) {
                float xv = bs2f((ushort)v_cur[j]);
                sa[j] += xv;
                sq[j] += xv * xv;
                mn[j] = fminf(mn[j], xv);
                mx[j] = fmaxf(mx[j], xv);
            }
            v_cur = v_nxt;
            r_nxt = r_fut;
            k += 6;
        }
    }
    // merge: slots 3..5 -> 0..2, then 1,2 -> 0
#pragma unroll
    for (int j = 0; j < 8; j++) {
        sa[j] += __shfl(sa[j], lane + 30);
        sq[j] += __shfl(sq[j], lane + 30);
        mn[j] = fminf(mn[j], __shfl(mn[j], lane + 30));
        mx[j] = fmaxf(mx[j], __shfl(mx[j], lane + 30));
    }
#pragma unroll
    for (int j = 0; j < 8; j++) {
        sa[j] += __shfl(sa[j], lane + 10) + __shfl(sa[j], lane + 20);
        sq[j] += __shfl(sq[j], lane + 10) + __shfl(sq[j], lane + 20);
        mn[j] = fminf(mn[j], fminf(__shfl(mn[j], lane + 10), __shfl(mn[j], lane + 20)));
        mx[j] = fmaxf(mx[j], fmaxf(__shfl(mx[j], lane + 10), __shfl(mx[j], lane + 20)));
    }

    if (lane < 10) {
        float cf = (float)deg;
        float inv = 1.f / fmaxf(cf, 1.f);
        const float* up = U + (size_t)i * 80 + lane * 8;
        float4 u0 = *(const float4*)up;
        float4 u1 = *(const float4*)(up + 4);
        float u[8] = {u0.x, u0.y, u0.z, u0.w, u1.x, u1.y, u1.z, u1.w};
        bf16x8 vmean, vmin, vmax, vstd;
#pragma unroll
        for (int j = 0; j < 8; j++) {
            float m = (u[j] * cf + sa[j]) * inv;
            float ev = sa[j] * inv;
            float st = sqrtf(fmaxf(sq[j] * inv - ev * ev, 0.f) + EPS);
            float mno = (deg > 0) ? (u[j] + mn[j]) : 0.f;
            float mxo = (deg > 0) ? (u[j] + mx[j]) : 0.f;
            vmean[j] = (short)f2bs(m);
            vmin[j] = (short)f2bs(mno);
            vmax[j] = (short)f2bs(mxo);
            vstd[j] = (short)f2bs(st);
        }
        ushort* a = hagg + (size_t)i * KPOST;
        *(bf16x8*)(a + 80 + lane * 8) = vmean;
        *(bf16x8*)(a + 160 + lane * 8) = vmin;
        *(bf16x8*)(a + 240 + lane * 8) = vmax;
        *(bf16x8*)(a + 320 + lane * 8) = vstd;
    } else if (lane < 12) {
        *(bf16x8*)(hagg + (size_t)i * KPOST + 400 + (lane - 10) * 8) =
            (bf16x8){0, 0, 0, 0, 0, 0, 0, 0};
    }
}

// ---------------- post GEMM + combine + lin GEMM + BN stats (1 wave = 32 rows) ----------------

__global__ __launch_bounds__(64) void post_lin_kernel(
    const ushort* __restrict__ A, const ushort* __restrict__ BT,
    const ushort* __restrict__ BL, const float* __restrict__ amp,
    const float* __restrict__ att, float* __restrict__ o2,
    float* __restrict__ slots) {
    __shared__ __align__(16) ushort olds[32 * 104];
    int lane = threadIdx.x;
    int col16 = lane & 15, quad = lane >> 4, kseg = quad * 8;
    int n0 = blockIdx.x * 32;
    const ushort* arowA = A + (size_t)(n0 + col16) * KPOST + kseg;
    const ushort* arowB = arowA + (size_t)16 * KPOST;
    const ushort* bbase = BT + (size_t)col16 * KPOST + kseg;

    f32x4 accA[15], accB[15];
#pragma unroll
    for (int i = 0; i < 15; i++) {
        accA[i] = (f32x4){0.f, 0.f, 0.f, 0.f};
        accB[i] = (f32x4){0.f, 0.f, 0.f, 0.f};
    }

    for (int kt = 0; kt < 13; kt++) {
        bf16x8 afA = *(const bf16x8*)(arowA + kt * 32);
        bf16x8 afB = *(const bf16x8*)(arowB + kt * 32);
#pragma unroll
        for (int nt = 0; nt < 15; nt++) {
            bf16x8 bfr = *(const bf16x8*)(bbase + (size_t)nt * (16 * KPOST) + kt * 32);
            accA[nt] = __builtin_amdgcn_mfma_f32_16x16x32_bf16(afA, bfr, accA[nt], 0, 0, 0);
            accB[nt] = __builtin_amdgcn_mfma_f32_16x16x32_bf16(afB, bfr, accB[nt], 0, 0, 0);
        }
    }
    float ampA[4], attA[4], ampB[4], attB[4];
#pragma unroll
    for (int r = 0; r < 4; r++) {
        int n = n0 + quad * 4 + r;
        ampA[r] = amp[n];
        attA[r] = att[n];
        ampB[r] = amp[n + 16];
        attB[r] = att[n + 16];
    }
#pragma unroll
    for (int g = 0; g < 5; g++) {
        int col = g * 16 + col16;
#pragma unroll
        for (int r = 0; r < 4; r++) {
            float ovA = accA[g][r] + ampA[r] * accA[g + 5][r] + attA[r] * accA[g + 10][r];
            float ovB = accB[g][r] + ampB[r] * accB[g + 5][r] + attB[r] * accB[g + 10][r];
            olds[(quad * 4 + r) * 104 + col] = (col < FF) ? f2bs(ovA) : (ushort)0;
            olds[(16 + quad * 4 + r) * 104 + col] = (col < FF) ? f2bs(ovB) : (ushort)0;
        }
    }
    {
        int rr = lane >> 1, cc = 80 + (lane & 1) * 8;
        *(bf16x8*)(olds + rr * 104 + cc) = (bf16x8){0, 0, 0, 0, 0, 0, 0, 0};
    }
    __syncthreads();

    f32x4 acc2A[5], acc2B[5];
#pragma unroll
    for (int i = 0; i < 5; i++) {
        acc2A[i] = (f32x4){0.f, 0.f, 0.f, 0.f};
        acc2B[i] = (f32x4){0.f, 0.f, 0.f, 0.f};
    }
    const ushort* blbase = BL + (size_t)col16 * KLIN + kseg;
#pragma unroll
    for (int kt = 0; kt < 3; kt++) {
        bf16x8 afA = *(const bf16x8*)(olds + col16 * 104 + kt * 32 + kseg);
        bf16x8 afB = *(const bf16x8*)(olds + (16 + col16) * 104 + kt * 32 + kseg);
#pragma unroll
        for (int nt = 0; nt < 5; nt++) {
            bf16x8 bfr = *(const bf16x8*)(blbase + nt * (16 * KLIN) + kt * 32);
            acc2A[nt] = __builtin_amdgcn_mfma_f32_16x16x32_bf16(afA, bfr, acc2A[nt], 0, 0, 0);
            acc2B[nt] = __builtin_amdgcn_mfma_f32_16x16x32_bf16(afB, bfr, acc2B[nt], 0, 0, 0);
        }
    }
    float* slot = slots + (blockIdx.x & 31) * 160;
#pragma unroll
    for (int nt = 0; nt < 5; nt++) {
        int col = nt * 16 + col16;
        float s = 0.f, q = 0.f;
#pragma unroll
        for (int r = 0; r < 4; r++) {
            int nA = n0 + quad * 4 + r;
            float vA = acc2A[nt][r];
            float vB = acc2B[nt][r];
            if (col < FF) {
                o2[(size_t)nA * 80 + col] = vA;
                o2[(size_t)(nA + 16) * 80 + col] = vB;
                s += vA + vB;
                q += vA * vA + vB * vB;
            }
        }
        s += __shfl_xor(s, 16); s += __shfl_xor(s, 32);
        q += __shfl_xor(q, 16); q += __shfl_xor(q, 32);
        if (lane < 16 && col < FF) {
            gAtomicAdd(&slot[col], s);
            gAtomicAdd(&slot[80 + col], q);
        }
    }
}

// ---------------- pool (BN inline) + final MLP fused: one block per graph ----------------

__global__ __launch_bounds__(256) void pool_mlp_kernel(
    const float* __restrict__ o2, const float* __restrict__ slots,
    const float* __restrict__ bg, const float* __restrict__ bb,
    const int* __restrict__ batch,
    const float* __restrict__ w1, const float* __restrict__ b1,
    const float* __restrict__ w2, const float* __restrict__ b2,
    const float* __restrict__ w3, const float* __restrict__ b3,
    float* __restrict__ out) {
    __shared__ float ssL[160];
    __shared__ float part[3][80];
    __shared__ float gr[80], h1[50], h2[25];
    int gi = blockIdx.x, tid = threadIdx.x;
    for (int c = tid; c < 80; c += 256) {
        if (c < FF) {
            float su = 0.f, sq = 0.f;
#pragma unroll 8
            for (int s = 0; s < 32; s++) {
                su += slots[s * 160 + c];
                sq += slots[s * 160 + 80 + c];
            }
            float mu = su * (1.f / (float)NN);
            float var = sq * (1.f / (float)NN) - mu * mu;
            float sc = bg[c] * rsqrtf(var + EPS);
            ssL[c] = sc;
            ssL[80 + c] = bb[c] - mu * sc;
        } else {
            ssL[c] = 0.f;
            ssL[80 + c] = 0.f;
        }
    }
    __syncthreads();
    int lo, hi;
    {
        int a = 0, b = NN;
        while (a < b) { int m = (a + b) >> 1; if (batch[m] < gi) a = m + 1; else b = m; }
        lo = a;
        b = NN;
        while (a < b) { int m = (a + b) >> 1; if (batch[m] < gi + 1) a = m + 1; else b = m; }
        hi = a;
    }
    if (tid < 240) {
        int c = tid % 80, sub = tid / 80;
        float acc = 0.f;
        if (c < FF) {
            for (int n = lo + sub; n < hi; n += 3)
                acc += fmaxf(o2[(size_t)n * 80 + c] * ssL[c] + ssL[80 + c], 0.f);
        }
        part[sub][c] = acc;
    }
    __syncthreads();
    if (tid < 80) gr[tid] = part[0][tid] + part[1][tid] + part[2][tid];
    __syncthreads();
    if (tid < 50) {
        float a = b1[tid];
        for (int k = 0; k < FF; k++) a += gr[k] * w1[k * 50 + tid];
        h1[tid] = fmaxf(a, 0.f);
    }
    __syncthreads();
    if (tid < 25) {
        float a = b2[tid];
        for (int k = 0; k < 50; k++) a += h1[k] * w2[k * 25 + tid];
        h2[tid] = fmaxf(a, 0.f);
    }
    __syncthreads();
    if (tid < 10) {
        float a = b3[tid];
        for (int k = 0; k < 25; k++) a += h2[k] * w3[k * 10 + tid];
        out[gi * 10 + tid] = a;
    }
}

// ---------------- launch ----------------

extern "C" void kernel_launch(void* const* d_in, const int* in_sizes, int n_in,
                              void* d_out, int out_size, void* d_ws, size_t ws_size,
                              hipStream_t stream) {
    const float* x = (const float*)d_in[0];
    const int* ei = (const int*)d_in[1];
    const int* batch = (const int*)d_in[2];
    const float* gcn_w = (const float*)d_in[3];
    const float* gcn_b = (const float*)d_in[4];
    const float* pre_w = (const float*)d_in[5];
    const float* pre_b = (const float*)d_in[6];
    const float* post_w = (const float*)d_in[7];
    const float* lin_w = (const float*)d_in[9];
    const float* bn_g = (const float*)d_in[11];
    const float* bn_b = (const float*)d_in[12];
    const float* w1 = (const float*)d_in[13];
    const float* b1 = (const float*)d_in[14];
    const float* w2 = (const float*)d_in[15];
    const float* b2 = (const float*)d_in[16];
    const float* w3 = (const float*)d_in[17];
    const float* b3 = (const float*)d_in[18];
    float* out = (float*)d_out;

    const int* row = ei;
    const int* col = ei + EE;

    char* ws = (char*)d_ws;
    size_t off = 0;
    auto alloc = [&](size_t bytes) {
        char* p = ws + off;
        off += (bytes + 255) & ~(size_t)255;
        return p;
    };
    // zero-region: cnt + scal(+slots) + gcur adjacent, single memset
    size_t z0 = off;
    int* cnt = (int*)alloc(NN * 4);
    float* scal = (float*)alloc((1 + LL * 32 * 160) * 4);  // [0]=sumlog; slots[5][32][160]
    int* gcur = (int*)alloc(256);
    size_t z1 = off;
    float* slotbase = scal + 1;
    int* offs = (int*)alloc(NN * 4);
    int* cursor = (int*)alloc(NN * 4);
    int* csr = (int*)alloc(EE * 4);
    float* dinv = (float*)alloc(NN * 4);
    float* amp = (float*)alloc(NN * 4);
    float* att = (float*)alloc(NN * 4);
    float* o2 = (float*)alloc((size_t)NN * 80 * 4);
    float* ubuf = (float*)alloc((size_t)NN * 80 * 4);
    ushort* xsbuf = (ushort*)alloc((size_t)NN * 80 * 2);
    ushort* vbuf = (ushort*)alloc((size_t)NN * 80 * 2);
    ushort* hagg = (ushort*)alloc((size_t)NN * KPOST * 2);
    ushort* BTuv = (ushort*)alloc((size_t)S_UV * 2);
    ushort* BTpost = (ushort*)alloc((size_t)S_POST * 2);
    ushort* BTlin = (ushort*)alloc((size_t)S_LIN * 2);

    hipMemsetAsync(ws + z0, 0, z1 - z0, stream);

    const int B = 256;
    const int NB = (NN + 255) / 256;  // 79
    countprep_kernel<<<(EE + S_TOT + B - 1) / B, B, 0, stream>>>(col, cnt, pre_w, pre_b,
                                                                 post_w, lin_w,
                                                                 BTuv, BTpost, BTlin);
    dinv_offs_kernel<<<NB, B, 0, stream>>>(cnt, dinv, scal, gcur, offs, cursor, NN);
    fill_xs_kernel<<<(EE + NN * 80 + B - 1) / B, B, 0, stream>>>(row, col, cursor, csr,
                                                                 x, gcn_w, dinv, xsbuf);
    gcn_kernel<<<NN / 4, B, 0, stream>>>(xsbuf, dinv, offs, csr, gcn_b, cnt, scal,
                                         o2, amp, att);

    const int GS2 = NN / 32;  // 625 single-wave blocks, 32 rows each
    for (int l = 0; l < LL; l++) {
        float* slots = slotbase + (size_t)l * 32 * 160;
        int lp = (l > 0) ? (l - 1) : 0;
        int ab = (l > 0) ? 1 : 0;
        const float* sp = (l == 0) ? slotbase : slotbase + (size_t)(l - 1) * 32 * 160;

        uv_bn_kernel<<<GS2, 64, 0, stream>>>(o2, sp, bn_g + lp * FF, bn_b + lp * FF, ab,
                                             BTuv + (size_t)l * NUV * KUV, ubuf, vbuf, hagg);
        edge_agg_kernel<<<NN / 4, B, 0, stream>>>(ubuf, vbuf, offs, csr, cnt, hagg);
        post_lin_kernel<<<GS2, 64, 0, stream>>>(hagg, BTpost + (size_t)l * 240 * KPOST,
                                                BTlin + (size_t)l * 80 * KLIN, amp, att,
                                                o2, slots);
    }

    pool_mlp_kernel<<<GG, B, 0, stream>>>(o2, slotbase + (size_t)(LL - 1) * 32 * 160,
                                          bn_g + (LL - 1) * FF, bn_b + (LL - 1) * FF,
                                          batch, w1, b1, w2, b2, w3, b3, out);
}